// Round 4
// baseline (604.118 us; speedup 1.0000x reference)
//
#include <hip/hip_runtime.h>
#include <math.h>

#define T_SEQ 1024
#define FEAT  512
#define NH    8
#define DKH   64

typedef __attribute__((ext_vector_type(8))) short          bf16x8;
typedef _Float16 f16;
typedef __attribute__((ext_vector_type(8))) _Float16       f16x8;
typedef __attribute__((ext_vector_type(4))) float          f32x4;
typedef __attribute__((ext_vector_type(8))) unsigned short u16x8;
typedef __attribute__((ext_vector_type(4))) unsigned short u16x4;

__device__ __forceinline__ float bf2f(unsigned short u) {
    union { unsigned int i; float f; } x; x.i = ((unsigned int)u) << 16; return x.f;
}
__device__ __forceinline__ unsigned short f2bf(float f) {
    union { float f; unsigned int i; } x; x.f = f;
    unsigned int r = x.i + 0x7FFFu + ((x.i >> 16) & 1u);
    return (unsigned short)(r >> 16);
}
__device__ __forceinline__ unsigned short f2h_bits(float f) {
    const f16 h = (f16)f;
    union { f16 h; unsigned short u; } x; x.h = h; return x.u;
}

// ---------------------------------------------------------------------------
// Pre-split the 5 weight matrices fp32 -> (hi, lo) bf16
// ---------------------------------------------------------------------------
struct WSplit {
    const float*    src[5];
    unsigned short* hi[5];
    unsigned short* lo[5];
};

__global__ __launch_bounds__(256)
void split_weights(WSplit pk) {
    const int ten = blockIdx.y;
    const float4* s = (const float4*)pk.src[ten];
    u16x4* dh = (u16x4*)pk.hi[ten];
    u16x4* dl = (u16x4*)pk.lo[ten];
    const int n4 = FEAT * FEAT / 4;
    for (int i = blockIdx.x * blockDim.x + threadIdx.x; i < n4;
         i += gridDim.x * blockDim.x) {
        const float4 v = s[i];
        float a[4] = {v.x, v.y, v.z, v.w};
        u16x4 h, l;
#pragma unroll
        for (int j = 0; j < 4; ++j) {
            h[j] = f2bf(a[j]);
            l[j] = f2bf(a[j] - bf2f(h[j]));
        }
        dh[i] = h; dl[i] = l;
    }
}

// ---------------------------------------------------------------------------
// Split-bf16 GEMM: C[M,N] = A[M,K] @ W[N,K]^T (+bias)
// 64x64 tile, 256 threads (4 waves, each 32x32), BK=32, 3 MFMAs/frag-pair.
// grid: (M/64, N/64) -> 1024 blocks for M=8192 -> 4 blocks/CU, 4 waves/SIMD.
// OUTMODE 0: fp32 C[M,N]; 1: f16 C[M,N]; 2: f16 V^T layout [b][col][t]
// ---------------------------------------------------------------------------
template<int OUTMODE>
__global__ __launch_bounds__(256)
void gemm_split(const float* __restrict__ A,
                const unsigned short* __restrict__ Wh,
                const unsigned short* __restrict__ Wl,
                const float* __restrict__ bias,
                void* __restrict__ Cout, int M, int N, int K)
{
    __shared__ unsigned short Ah[64][40];
    __shared__ unsigned short Al[64][40];
    __shared__ unsigned short Bh[64][40];
    __shared__ unsigned short Bl[64][40];

    const int tid  = threadIdx.x;
    const int w    = tid >> 6, lane = tid & 63, g = lane >> 4, c = lane & 15;
    const int m0   = blockIdx.x * 64, n0 = blockIdx.y * 64;
    const int wr   = (w >> 1) * 32, wc = (w & 1) * 32;
    const int r0   = tid >> 2, ch = tid & 3;      // staging row 0..63, chunk 0..3

    f32x4 acc[2][2];
#pragma unroll
    for (int m = 0; m < 2; ++m)
#pragma unroll
        for (int n = 0; n < 2; ++n)
#pragma unroll
            for (int r = 0; r < 4; ++r) acc[m][n][r] = 0.f;

    float4 ar[2];
    u16x8  brh, brl;
    auto ldA = [&](int kc) {
        const int gr = m0 + r0;
        if (gr < M) {
            const size_t base = (size_t)gr * K + kc * 32 + ch * 8;
            ar[0] = *(const float4*)&A[base];
            ar[1] = *(const float4*)&A[base + 4];
        } else {
            ar[0] = make_float4(0.f, 0.f, 0.f, 0.f);
            ar[1] = make_float4(0.f, 0.f, 0.f, 0.f);
        }
    };
    auto ldB = [&](int kc) {
        const size_t base = (size_t)(n0 + r0) * K + kc * 32 + ch * 8;
        brh = *(const u16x8*)&Wh[base];
        brl = *(const u16x8*)&Wl[base];
    };

    ldA(0); ldB(0);

    const int nk = K / 32;
    for (int kc = 0; kc < nk; ++kc) {
        __syncthreads();
        {
            float v[8] = {ar[0].x, ar[0].y, ar[0].z, ar[0].w,
                          ar[1].x, ar[1].y, ar[1].z, ar[1].w};
            u16x8 h, l;
#pragma unroll
            for (int j = 0; j < 8; ++j) {
                h[j] = f2bf(v[j]);
                l[j] = f2bf(v[j] - bf2f(h[j]));
            }
            *(u16x8*)&Ah[r0][ch * 8] = h;
            *(u16x8*)&Al[r0][ch * 8] = l;
            *(u16x8*)&Bh[r0][ch * 8] = brh;
            *(u16x8*)&Bl[r0][ch * 8] = brl;
        }
        __syncthreads();
        if (kc + 1 < nk) { ldA(kc + 1); ldB(kc + 1); }

        bf16x8 ah[2], al[2], bh[2], bl[2];
#pragma unroll
        for (int m = 0; m < 2; ++m) {
            ah[m] = *(const bf16x8*)&Ah[wr + 16 * m + c][8 * g];
            al[m] = *(const bf16x8*)&Al[wr + 16 * m + c][8 * g];
        }
#pragma unroll
        for (int n = 0; n < 2; ++n) {
            bh[n] = *(const bf16x8*)&Bh[wc + 16 * n + c][8 * g];
            bl[n] = *(const bf16x8*)&Bl[wc + 16 * n + c][8 * g];
        }
#pragma unroll
        for (int m = 0; m < 2; ++m)
#pragma unroll
            for (int n = 0; n < 2; ++n) {
                acc[m][n] = __builtin_amdgcn_mfma_f32_16x16x32_bf16(ah[m], bh[n], acc[m][n], 0, 0, 0);
                acc[m][n] = __builtin_amdgcn_mfma_f32_16x16x32_bf16(ah[m], bl[n], acc[m][n], 0, 0, 0);
                acc[m][n] = __builtin_amdgcn_mfma_f32_16x16x32_bf16(al[m], bh[n], acc[m][n], 0, 0, 0);
            }
    }

#pragma unroll
    for (int n = 0; n < 2; ++n) {
        const int gcol = n0 + wc + 16 * n + c;
        const float bb = bias ? bias[gcol] : 0.f;
#pragma unroll
        for (int m = 0; m < 2; ++m) {
            if (OUTMODE == 2) {
                const int grb = m0 + wr + 16 * m + 4 * g;
                const int bidx = grb >> 10, t = grb & 1023;
                u16x4 pk4;
#pragma unroll
                for (int r = 0; r < 4; ++r) pk4[r] = f2h_bits(acc[m][n][r] + bb);
                *(u16x4*)&((unsigned short*)Cout)[((size_t)(bidx * FEAT + gcol)) * T_SEQ + t] = pk4;
            } else {
#pragma unroll
                for (int r = 0; r < 4; ++r) {
                    const int gr = m0 + wr + 16 * m + 4 * g + r;
                    if (gr < M) {
                        const float v = acc[m][n][r] + bb;
                        if (OUTMODE == 0) ((float*)Cout)[(size_t)gr * N + gcol] = v;
                        else ((unsigned short*)Cout)[(size_t)gr * N + gcol] = f2h_bits(v);
                    }
                }
            }
        }
    }
}

// ---------------------------------------------------------------------------
// fp16-MFMA relative-position flash attention.
// 64 q-rows/block, 4 waves, Q-frags hoisted to registers.
// bd[t,s] = q_v[t] . p[(T-1) - t + s]; bd stored TRANSPOSED bdT[p][t] so the
// D-layout write packs 4 consecutive rows into one u16x4 (conflict-free).
// LDS (ushort, stride 68): kt 64x68, vtT 64x68, pt 128x68 (ps aliases rows
// 0..63 after bar C), bdT 128x68.  Total 52224 B -> 3 blocks/CU.
// ---------------------------------------------------------------------------
#define AST 68

__global__ __launch_bounds__(256)
void attn_f16(const unsigned short* __restrict__ qb,
              const unsigned short* __restrict__ kb,
              const unsigned short* __restrict__ vtg,   // V^T [b][feat][t], f16
              const unsigned short* __restrict__ pb,    // [2047][FEAT], f16
              const int* __restrict__ mask,
              const float* __restrict__ pbu, const float* __restrict__ pbv,
              float* __restrict__ xout)
{
    extern __shared__ unsigned short sm[];
    unsigned short* kt  = sm;                 // 64*AST
    unsigned short* vtT = kt  + 64 * AST;     // 64*AST
    unsigned short* pt  = vtT + 64 * AST;     // 128*AST (ps aliases rows 0..63)
    unsigned short* bdT = pt  + 128 * AST;    // 128*AST
    f16* bdf = (f16*)bdT;
    f16* psf = (f16*)pt;

    const int tid = threadIdx.x;
    const int w = tid >> 6, lane = tid & 63, g = lane >> 4, c = lane & 15;
    const int t0 = blockIdx.x * 64;
    const int b  = blockIdx.y >> 3, h = blockIdx.y & 7;

    const unsigned short* ksrc = kb + ((size_t)b * T_SEQ) * FEAT + h * DKH;
    const unsigned short* vsrc = vtg + ((size_t)(b * FEAT + h * DKH)) * T_SEQ;
    const unsigned short* psrc = pb + h * DKH;

    // ---- Q fragments directly to registers (loop-invariant; A-frag row = c)
    f16x8 aq0, aq1, av0, av1;
    {
        const unsigned short* qp =
            qb + ((size_t)(b * T_SEQ + t0 + 16 * w + c)) * FEAT + h * DKH + 8 * g;
        const f16x8 q0 = *(const f16x8*)qp;
        const f16x8 q1 = *(const f16x8*)(qp + 32);
        const float* pu = pbu + h * DKH + 8 * g;
        const float* pv = pbv + h * DKH + 8 * g;
#pragma unroll
        for (int j = 0; j < 8; ++j) {
            const float f0 = (float)q0[j], f1 = (float)q1[j];
            aq0[j] = (f16)(f0 + pu[j]);       av0[j] = (f16)(f0 + pv[j]);
            aq1[j] = (f16)(f1 + pu[j + 32]);  av1[j] = (f16)(f1 + pv[j + 32]);
        }
    }

    f32x4 accO[4];
    float m_r[4], l_r[4];
#pragma unroll
    for (int n = 0; n < 4; ++n)
#pragma unroll
        for (int r = 0; r < 4; ++r) accO[n][r] = 0.f;
#pragma unroll
    for (int r = 0; r < 4; ++r) { m_r[r] = -3.0e38f; l_r[r] = 0.f; }

    for (int st = 0; st < 16; ++st) {
        const int s0 = st * 64;
        const int pbase = (T_SEQ - DKH) - t0 + s0;   // p row = pbase + (63 - ti + si)
        __syncthreads();   // A: prev-iter PV reads done
#pragma unroll
        for (int q2 = 0; q2 < 2; ++q2) {
            const int id = tid + 256 * q2, row = id >> 3, chq = id & 7;
            *(u16x8*)&kt[row * AST + chq * 8] =
                *(const u16x8*)&ksrc[(size_t)(s0 + row) * FEAT + chq * 8];
            *(u16x8*)&vtT[row * AST + chq * 8] =
                *(const u16x8*)&vsrc[(size_t)row * T_SEQ + s0 + chq * 8];
        }
#pragma unroll
        for (int q2 = 0; q2 < 4; ++q2) {
            const int id = tid + 256 * q2, prow = id >> 3, chq = id & 7;
            u16x8 p8;
            if (prow < 127)
                p8 = *(const u16x8*)&psrc[(size_t)(pbase + prow) * FEAT + chq * 8];
            else {
#pragma unroll
                for (int j = 0; j < 8; ++j) p8[j] = 0;
            }
            *(u16x8*)&pt[prow * AST + chq * 8] = p8;
        }
        __syncthreads();   // B: tiles ready

        // ---- AC = (q+u) K^T
        f32x4 acS[4];
#pragma unroll
        for (int j = 0; j < 4; ++j)
#pragma unroll
            for (int r = 0; r < 4; ++r) acS[j][r] = 0.f;
#pragma unroll
        for (int j = 0; j < 4; ++j) {
            const f16x8 b0 = *(const f16x8*)&kt[(16 * j + c) * AST + 8 * g];
            const f16x8 b1 = *(const f16x8*)&kt[(16 * j + c) * AST + 32 + 8 * g];
            acS[j] = __builtin_amdgcn_mfma_f32_16x16x32_f16(aq0, b0, acS[j], 0, 0, 0);
            acS[j] = __builtin_amdgcn_mfma_f32_16x16x32_f16(aq1, b1, acS[j], 0, 0, 0);
        }

        // ---- BD = (q+v) P_window^T, stored transposed: bdT[p][t], u16x4 pack
#pragma unroll
        for (int jj = 0; jj < 8; ++jj) {
            f32x4 bda;
#pragma unroll
            for (int r = 0; r < 4; ++r) bda[r] = 0.f;
            const f16x8 b0 = *(const f16x8*)&pt[(16 * jj + c) * AST + 8 * g];
            const f16x8 b1 = *(const f16x8*)&pt[(16 * jj + c) * AST + 32 + 8 * g];
            bda = __builtin_amdgcn_mfma_f32_16x16x32_f16(av0, b0, bda, 0, 0, 0);
            bda = __builtin_amdgcn_mfma_f32_16x16x32_f16(av1, b1, bda, 0, 0, 0);
            u16x4 pk4;
#pragma unroll
            for (int r = 0; r < 4; ++r) pk4[r] = f2h_bits(bda[r]);
            *(u16x4*)&bdT[(16 * jj + c) * AST + 16 * w + 4 * g] = pk4;
        }
        __syncthreads();   // C: bdT visible; pt dead -> ps can use it

        // ---- online softmax; rows ti = 16w+4g+r, cols si = 16j+c
        int mk[4];
#pragma unroll
        for (int j = 0; j < 4; ++j) mk[j] = mask[b * T_SEQ + s0 + 16 * j + c];
#pragma unroll
        for (int r = 0; r < 4; ++r) {
            const int ti = 16 * w + 4 * g + r;
            const int sh = 63 - ti;
            float sv[4];
#pragma unroll
            for (int j = 0; j < 4; ++j) {
                const float bdv = (float)bdf[(sh + 16 * j + c) * AST + ti];
                sv[j] = (mk[j] == 0) ? -1.0e30f : (acS[j][r] + bdv) * 0.125f;
            }
            float mx = fmaxf(fmaxf(sv[0], sv[1]), fmaxf(sv[2], sv[3]));
            mx = fmaxf(mx, __shfl_xor(mx, 1)); mx = fmaxf(mx, __shfl_xor(mx, 2));
            mx = fmaxf(mx, __shfl_xor(mx, 4)); mx = fmaxf(mx, __shfl_xor(mx, 8));
            const float mnew = fmaxf(m_r[r], mx);
            const float corr = __expf(m_r[r] - mnew);
            m_r[r] = mnew;
            float rs = 0.f;
#pragma unroll
            for (int j = 0; j < 4; ++j) {
                const float e = (mk[j] == 0) ? 0.f : __expf(sv[j] - mnew);
                rs += e;
                psf[ti * AST + 16 * j + c] = (f16)e;
            }
            rs += __shfl_xor(rs, 1); rs += __shfl_xor(rs, 2);
            rs += __shfl_xor(rs, 4); rs += __shfl_xor(rs, 8);
            l_r[r] = l_r[r] * corr + rs;
#pragma unroll
            for (int n = 0; n < 4; ++n) accO[n][r] *= corr;
        }
        __syncthreads();   // D: P visible

        // ---- PV: O += P V
        const f16x8 pa0 = *(const f16x8*)&pt[(16 * w + c) * AST + 8 * g];
        const f16x8 pa1 = *(const f16x8*)&pt[(16 * w + c) * AST + 32 + 8 * g];
#pragma unroll
        for (int n = 0; n < 4; ++n) {
            const f16x8 b0 = *(const f16x8*)&vtT[(16 * n + c) * AST + 8 * g];
            const f16x8 b1 = *(const f16x8*)&vtT[(16 * n + c) * AST + 32 + 8 * g];
            accO[n] = __builtin_amdgcn_mfma_f32_16x16x32_f16(pa0, b0, accO[n], 0, 0, 0);
            accO[n] = __builtin_amdgcn_mfma_f32_16x16x32_f16(pa1, b1, accO[n], 0, 0, 0);
        }
    }

    // ---- epilogue: fp32 x
#pragma unroll
    for (int r = 0; r < 4; ++r) {
        const float inv = (l_r[r] > 0.f) ? 1.0f / l_r[r] : 0.f;
        const int t = t0 + 16 * w + 4 * g + r;
#pragma unroll
        for (int n = 0; n < 4; ++n)
            xout[((size_t)(b * T_SEQ + t)) * FEAT + h * DKH + 16 * n + c] = accO[n][r] * inv;
    }
}

// ---------------------------------------------------------------------------
extern "C" void kernel_launch(void* const* d_in, const int* in_sizes, int n_in,
                              void* d_out, int out_size, void* d_ws, size_t ws_size,
                              hipStream_t stream)
{
    (void)in_sizes; (void)n_in; (void)out_size; (void)ws_size;
    const float* query   = (const float*)d_in[0];
    const float* key_in  = (const float*)d_in[1];
    const float* value   = (const float*)d_in[2];
    const float* pos_emb = (const float*)d_in[3];
    const int*   mask    = (const int*)  d_in[4];
    const float* Wq = (const float*)d_in[5];
    const float* bq = (const float*)d_in[6];
    const float* Wk = (const float*)d_in[7];
    const float* bk = (const float*)d_in[8];
    const float* Wv = (const float*)d_in[9];
    const float* bv = (const float*)d_in[10];
    const float* Wo = (const float*)d_in[11];
    const float* bo = (const float*)d_in[12];
    const float* Wp = (const float*)d_in[13];
    const float* pbu = (const float*)d_in[14];
    const float* pbv = (const float*)d_in[15];
    float* out = (float*)d_out;

    const size_t NTOK = (size_t)8 * T_SEQ;       // 8192
    char* wsp = (char*)d_ws;
    size_t off = 0;
    auto alloc = [&](size_t bytes) { char* p = wsp + off; off += (bytes + 255) & ~255ull; return p; };

    unsigned short* qbf = (unsigned short*)alloc(NTOK * FEAT * 2);        // f16
    unsigned short* kbf = (unsigned short*)alloc(NTOK * FEAT * 2);        // f16
    unsigned short* vTb = (unsigned short*)alloc(NTOK * FEAT * 2);        // f16 [b][feat][t]
    unsigned short* pbf = (unsigned short*)alloc((size_t)2047 * FEAT * 2);// f16
    float*          xbf = (float*)alloc(NTOK * FEAT * 4);                 // fp32
    unsigned short* wh[5]; unsigned short* wl[5];
    for (int i = 0; i < 5; ++i) {
        wh[i] = (unsigned short*)alloc((size_t)FEAT * FEAT * 2);
        wl[i] = (unsigned short*)alloc((size_t)FEAT * FEAT * 2);
    }

    WSplit sp;
    const float* wsrc[5] = {Wq, Wk, Wv, Wp, Wo};
    for (int i = 0; i < 5; ++i) { sp.src[i] = wsrc[i]; sp.hi[i] = wh[i]; sp.lo[i] = wl[i]; }
    split_weights<<<dim3(64, 5), 256, 0, stream>>>(sp);

    gemm_split<1><<<dim3(128, 8), 256, 0, stream>>>(query,  wh[0], wl[0], bq, qbf, 8192, FEAT, FEAT);
    gemm_split<1><<<dim3(128, 8), 256, 0, stream>>>(key_in, wh[1], wl[1], bk, kbf, 8192, FEAT, FEAT);
    gemm_split<2><<<dim3(128, 8), 256, 0, stream>>>(value,  wh[2], wl[2], bv, vTb, 8192, FEAT, FEAT);
    gemm_split<1><<<dim3(32, 8),  256, 0, stream>>>(pos_emb, wh[3], wl[3], nullptr, pbf, 2047, FEAT, FEAT);

    const int lds_bytes = 384 * AST * 2;   // 52224 -> 3 blocks/CU
    hipFuncSetAttribute((const void*)attn_f16,
                        hipFuncAttributeMaxDynamicSharedMemorySize, lds_bytes);
    attn_f16<<<dim3(16, 64), 256, lds_bytes, stream>>>(qbf, kbf, vTb, pbf,
                                                       mask, pbu, pbv, xbf);

    gemm_split<0><<<dim3(128, 8), 256, 0, stream>>>(xbf, wh[4], wl[4], bo, out, 8192, FEAT, FEAT);
}

// Round 5
// 386.918 us; speedup vs baseline: 1.5614x; 1.5614x over previous
//
#include <hip/hip_runtime.h>
#include <math.h>

#define T_SEQ 1024
#define FEAT  512
#define NH    8
#define DKH   64

typedef __attribute__((ext_vector_type(8))) short          bf16x8;
typedef _Float16 f16;
typedef __attribute__((ext_vector_type(8))) _Float16       f16x8;
typedef __attribute__((ext_vector_type(4))) float          f32x4;
typedef __attribute__((ext_vector_type(8))) unsigned short u16x8;
typedef __attribute__((ext_vector_type(4))) unsigned short u16x4;

__device__ __forceinline__ float bf2f(unsigned short u) {
    union { unsigned int i; float f; } x; x.i = ((unsigned int)u) << 16; return x.f;
}
__device__ __forceinline__ unsigned short f2bf(float f) {
    union { float f; unsigned int i; } x; x.f = f;
    unsigned int r = x.i + 0x7FFFu + ((x.i >> 16) & 1u);
    return (unsigned short)(r >> 16);
}
__device__ __forceinline__ unsigned short f2h_bits(float f) {
    const f16 h = (f16)f;
    union { f16 h; unsigned short u; } x; x.h = h; return x.u;
}

// ---------------------------------------------------------------------------
// Pre-split the 5 weight matrices fp32 -> (hi, lo) bf16
// ---------------------------------------------------------------------------
struct WSplit {
    const float*    src[5];
    unsigned short* hi[5];
    unsigned short* lo[5];
};

__global__ __launch_bounds__(256)
void split_weights(WSplit pk) {
    const int ten = blockIdx.y;
    const float4* s = (const float4*)pk.src[ten];
    u16x4* dh = (u16x4*)pk.hi[ten];
    u16x4* dl = (u16x4*)pk.lo[ten];
    const int n4 = FEAT * FEAT / 4;
    for (int i = blockIdx.x * blockDim.x + threadIdx.x; i < n4;
         i += gridDim.x * blockDim.x) {
        const float4 v = s[i];
        float a[4] = {v.x, v.y, v.z, v.w};
        u16x4 h, l;
#pragma unroll
        for (int j = 0; j < 4; ++j) {
            h[j] = f2bf(a[j]);
            l[j] = f2bf(a[j] - bf2f(h[j]));
        }
        dh[i] = h; dl[i] = l;
    }
}

// ---------------------------------------------------------------------------
// Split-bf16 GEMM: C[M,N] = A[M,K] @ W[N,K]^T (+bias)
// 64x64 tile, 256 threads (4 waves, each 32x32), BK=32, 3 MFMAs/frag-pair.
// grid (M/64, N/64) = 1024 blocks for M=8192 -> 4 blocks/CU. [R4: 243->184us]
// OUTMODE 0: fp32 C[M,N]; 1: f16 C[M,N]; 2: f16 V^T layout [b][col][t]
// ---------------------------------------------------------------------------
template<int OUTMODE>
__global__ __launch_bounds__(256)
void gemm_split(const float* __restrict__ A,
                const unsigned short* __restrict__ Wh,
                const unsigned short* __restrict__ Wl,
                const float* __restrict__ bias,
                void* __restrict__ Cout, int M, int N, int K)
{
    __shared__ unsigned short Ah[64][40];
    __shared__ unsigned short Al[64][40];
    __shared__ unsigned short Bh[64][40];
    __shared__ unsigned short Bl[64][40];

    const int tid  = threadIdx.x;
    const int w    = tid >> 6, lane = tid & 63, g = lane >> 4, c = lane & 15;
    const int m0   = blockIdx.x * 64, n0 = blockIdx.y * 64;
    const int wr   = (w >> 1) * 32, wc = (w & 1) * 32;
    const int r0   = tid >> 2, ch = tid & 3;

    f32x4 acc[2][2];
#pragma unroll
    for (int m = 0; m < 2; ++m)
#pragma unroll
        for (int n = 0; n < 2; ++n)
#pragma unroll
            for (int r = 0; r < 4; ++r) acc[m][n][r] = 0.f;

    float4 ar[2];
    u16x8  brh, brl;
    auto ldA = [&](int kc) {
        const int gr = m0 + r0;
        if (gr < M) {
            const size_t base = (size_t)gr * K + kc * 32 + ch * 8;
            ar[0] = *(const float4*)&A[base];
            ar[1] = *(const float4*)&A[base + 4];
        } else {
            ar[0] = make_float4(0.f, 0.f, 0.f, 0.f);
            ar[1] = make_float4(0.f, 0.f, 0.f, 0.f);
        }
    };
    auto ldB = [&](int kc) {
        const size_t base = (size_t)(n0 + r0) * K + kc * 32 + ch * 8;
        brh = *(const u16x8*)&Wh[base];
        brl = *(const u16x8*)&Wl[base];
    };

    ldA(0); ldB(0);

    const int nk = K / 32;
    for (int kc = 0; kc < nk; ++kc) {
        __syncthreads();
        {
            float v[8] = {ar[0].x, ar[0].y, ar[0].z, ar[0].w,
                          ar[1].x, ar[1].y, ar[1].z, ar[1].w};
            u16x8 h, l;
#pragma unroll
            for (int j = 0; j < 8; ++j) {
                h[j] = f2bf(v[j]);
                l[j] = f2bf(v[j] - bf2f(h[j]));
            }
            *(u16x8*)&Ah[r0][ch * 8] = h;
            *(u16x8*)&Al[r0][ch * 8] = l;
            *(u16x8*)&Bh[r0][ch * 8] = brh;
            *(u16x8*)&Bl[r0][ch * 8] = brl;
        }
        __syncthreads();
        if (kc + 1 < nk) { ldA(kc + 1); ldB(kc + 1); }

        bf16x8 ah[2], al[2], bh[2], bl[2];
#pragma unroll
        for (int m = 0; m < 2; ++m) {
            ah[m] = *(const bf16x8*)&Ah[wr + 16 * m + c][8 * g];
            al[m] = *(const bf16x8*)&Al[wr + 16 * m + c][8 * g];
        }
#pragma unroll
        for (int n = 0; n < 2; ++n) {
            bh[n] = *(const bf16x8*)&Bh[wc + 16 * n + c][8 * g];
            bl[n] = *(const bf16x8*)&Bl[wc + 16 * n + c][8 * g];
        }
#pragma unroll
        for (int m = 0; m < 2; ++m)
#pragma unroll
            for (int n = 0; n < 2; ++n) {
                acc[m][n] = __builtin_amdgcn_mfma_f32_16x16x32_bf16(ah[m], bh[n], acc[m][n], 0, 0, 0);
                acc[m][n] = __builtin_amdgcn_mfma_f32_16x16x32_bf16(ah[m], bl[n], acc[m][n], 0, 0, 0);
                acc[m][n] = __builtin_amdgcn_mfma_f32_16x16x32_bf16(al[m], bh[n], acc[m][n], 0, 0, 0);
            }
    }

#pragma unroll
    for (int n = 0; n < 2; ++n) {
        const int gcol = n0 + wc + 16 * n + c;
        const float bb = bias ? bias[gcol] : 0.f;
#pragma unroll
        for (int m = 0; m < 2; ++m) {
            if (OUTMODE == 2) {
                const int grb = m0 + wr + 16 * m + 4 * g;
                const int bidx = grb >> 10, t = grb & 1023;
                u16x4 pk4;
#pragma unroll
                for (int r = 0; r < 4; ++r) pk4[r] = f2h_bits(acc[m][n][r] + bb);
                *(u16x4*)&((unsigned short*)Cout)[((size_t)(bidx * FEAT + gcol)) * T_SEQ + t] = pk4;
            } else {
#pragma unroll
                for (int r = 0; r < 4; ++r) {
                    const int gr = m0 + wr + 16 * m + 4 * g + r;
                    if (gr < M) {
                        const float v = acc[m][n][r] + bb;
                        if (OUTMODE == 0) ((float*)Cout)[(size_t)gr * N + gcol] = v;
                        else ((unsigned short*)Cout)[(size_t)gr * N + gcol] = f2h_bits(v);
                    }
                }
            }
        }
    }
}

// ---------------------------------------------------------------------------
// fp16-MFMA relative-position flash attention — ROUND-3 LAYOUT (201us known-
// good: strides 72, row-major bdb @132, separate ps) + Q-register hoist only.
// R4 lesson: the 68-stride/bdT relayout cut conflicts 12.1M->2.1M but DOUBLED
// duration (stall-bound, not conflict-bound) — do not re-apply.
// LDS (ushort): kt 64x72, vtT 64x72, pt 128x72, ps 64x72, bdb 64x132
//   = 31488 ushort = 62976 B -> 2 blocks/CU.
// ---------------------------------------------------------------------------
#define AST  72
#define BDST 132

__global__ __launch_bounds__(256)
void attn_f16(const unsigned short* __restrict__ qb,
              const unsigned short* __restrict__ kb,
              const unsigned short* __restrict__ vtg,   // V^T [b][feat][t], f16
              const unsigned short* __restrict__ pb,    // [2047][FEAT], f16
              const int* __restrict__ mask,
              const float* __restrict__ pbu, const float* __restrict__ pbv,
              float* __restrict__ xout)
{
    extern __shared__ unsigned short sm[];
    unsigned short* kt  = sm;                 // 64*AST
    unsigned short* vtT = kt  + 64 * AST;     // 64*AST
    unsigned short* pt  = vtT + 64 * AST;     // 128*AST
    unsigned short* ps  = pt  + 128 * AST;    // 64*AST
    unsigned short* bdb = ps  + 64 * AST;     // 64*BDST
    f16* bdf = (f16*)bdb;
    f16* psf = (f16*)ps;

    const int tid = threadIdx.x;
    const int w = tid >> 6, lane = tid & 63, g = lane >> 4, c = lane & 15;
    const int t0 = blockIdx.x * 64;
    const int b  = blockIdx.y >> 3, h = blockIdx.y & 7;

    const unsigned short* ksrc = kb + ((size_t)b * T_SEQ) * FEAT + h * DKH;
    const unsigned short* vsrc = vtg + ((size_t)(b * FEAT + h * DKH)) * T_SEQ;
    const unsigned short* psrc = pb + h * DKH;

    // ---- Q fragments directly to registers (loop-invariant; A-frag row = c)
    f16x8 aq0, aq1, av0, av1;
    {
        const unsigned short* qp =
            qb + ((size_t)(b * T_SEQ + t0 + 16 * w + c)) * FEAT + h * DKH + 8 * g;
        const f16x8 q0 = *(const f16x8*)qp;
        const f16x8 q1 = *(const f16x8*)(qp + 32);
        const float* pu = pbu + h * DKH + 8 * g;
        const float* pv = pbv + h * DKH + 8 * g;
#pragma unroll
        for (int j = 0; j < 8; ++j) {
            const float f0 = (float)q0[j], f1 = (float)q1[j];
            aq0[j] = (f16)(f0 + pu[j]);       av0[j] = (f16)(f0 + pv[j]);
            aq1[j] = (f16)(f1 + pu[j + 32]);  av1[j] = (f16)(f1 + pv[j + 32]);
        }
    }

    f32x4 accO[4];
    float m_r[4], l_r[4];
#pragma unroll
    for (int n = 0; n < 4; ++n)
#pragma unroll
        for (int r = 0; r < 4; ++r) accO[n][r] = 0.f;
#pragma unroll
    for (int r = 0; r < 4; ++r) { m_r[r] = -3.0e38f; l_r[r] = 0.f; }

    for (int st = 0; st < 16; ++st) {
        const int s0 = st * 64;
        const int pbase = (T_SEQ - DKH) - t0 + s0;   // p row = pbase + (63 - ti + si)
        __syncthreads();   // A: prev-iter PV reads done
#pragma unroll
        for (int q2 = 0; q2 < 2; ++q2) {
            const int id = tid + 256 * q2, row = id >> 3, chq = id & 7;
            *(u16x8*)&kt[row * AST + chq * 8] =
                *(const u16x8*)&ksrc[(size_t)(s0 + row) * FEAT + chq * 8];
            *(u16x8*)&vtT[row * AST + chq * 8] =
                *(const u16x8*)&vsrc[(size_t)row * T_SEQ + s0 + chq * 8];
        }
#pragma unroll
        for (int q2 = 0; q2 < 4; ++q2) {
            const int id = tid + 256 * q2, prow = id >> 3, chq = id & 7;
            u16x8 p8;
            if (prow < 127)
                p8 = *(const u16x8*)&psrc[(size_t)(pbase + prow) * FEAT + chq * 8];
            else {
#pragma unroll
                for (int j = 0; j < 8; ++j) p8[j] = 0;
            }
            *(u16x8*)&pt[prow * AST + chq * 8] = p8;
        }
        __syncthreads();   // B: tiles ready

        // ---- AC = (q+u) K^T
        f32x4 acS[4];
#pragma unroll
        for (int j = 0; j < 4; ++j)
#pragma unroll
            for (int r = 0; r < 4; ++r) acS[j][r] = 0.f;
#pragma unroll
        for (int j = 0; j < 4; ++j) {
            const f16x8 b0 = *(const f16x8*)&kt[(16 * j + c) * AST + 8 * g];
            const f16x8 b1 = *(const f16x8*)&kt[(16 * j + c) * AST + 32 + 8 * g];
            acS[j] = __builtin_amdgcn_mfma_f32_16x16x32_f16(aq0, b0, acS[j], 0, 0, 0);
            acS[j] = __builtin_amdgcn_mfma_f32_16x16x32_f16(aq1, b1, acS[j], 0, 0, 0);
        }

        // ---- BD = (q+v) P_window^T -> bdb row-major [t][p], scalar writes
#pragma unroll
        for (int jj = 0; jj < 8; ++jj) {
            f32x4 bda;
#pragma unroll
            for (int r = 0; r < 4; ++r) bda[r] = 0.f;
            const f16x8 b0 = *(const f16x8*)&pt[(16 * jj + c) * AST + 8 * g];
            const f16x8 b1 = *(const f16x8*)&pt[(16 * jj + c) * AST + 32 + 8 * g];
            bda = __builtin_amdgcn_mfma_f32_16x16x32_f16(av0, b0, bda, 0, 0, 0);
            bda = __builtin_amdgcn_mfma_f32_16x16x32_f16(av1, b1, bda, 0, 0, 0);
#pragma unroll
            for (int r = 0; r < 4; ++r)
                bdf[(16 * w + 4 * g + r) * BDST + 16 * jj + c] = (f16)bda[r];
        }
        __syncthreads();   // C: bdb visible

        // ---- online softmax; rows ti = 16w+4g+r, cols si = 16j+c
        int mk[4];
#pragma unroll
        for (int j = 0; j < 4; ++j) mk[j] = mask[b * T_SEQ + s0 + 16 * j + c];
#pragma unroll
        for (int r = 0; r < 4; ++r) {
            const int ti = 16 * w + 4 * g + r;
            float sv[4];
#pragma unroll
            for (int j = 0; j < 4; ++j) {
                const float bdv = (float)bdf[ti * BDST + (63 - ti + 16 * j + c)];
                sv[j] = (mk[j] == 0) ? -1.0e30f : (acS[j][r] + bdv) * 0.125f;
            }
            float mx = fmaxf(fmaxf(sv[0], sv[1]), fmaxf(sv[2], sv[3]));
            mx = fmaxf(mx, __shfl_xor(mx, 1)); mx = fmaxf(mx, __shfl_xor(mx, 2));
            mx = fmaxf(mx, __shfl_xor(mx, 4)); mx = fmaxf(mx, __shfl_xor(mx, 8));
            const float mnew = fmaxf(m_r[r], mx);
            const float corr = __expf(m_r[r] - mnew);
            m_r[r] = mnew;
            float rs = 0.f;
#pragma unroll
            for (int j = 0; j < 4; ++j) {
                const float e = (mk[j] == 0) ? 0.f : __expf(sv[j] - mnew);
                rs += e;
                psf[ti * AST + 16 * j + c] = (f16)e;
            }
            rs += __shfl_xor(rs, 1); rs += __shfl_xor(rs, 2);
            rs += __shfl_xor(rs, 4); rs += __shfl_xor(rs, 8);
            l_r[r] = l_r[r] * corr + rs;
#pragma unroll
            for (int n = 0; n < 4; ++n) accO[n][r] *= corr;
        }
        __syncthreads();   // D: P visible

        // ---- PV: O += P V
        const f16x8 pa0 = *(const f16x8*)&ps[(16 * w + c) * AST + 8 * g];
        const f16x8 pa1 = *(const f16x8*)&ps[(16 * w + c) * AST + 32 + 8 * g];
#pragma unroll
        for (int n = 0; n < 4; ++n) {
            const f16x8 b0 = *(const f16x8*)&vtT[(16 * n + c) * AST + 8 * g];
            const f16x8 b1 = *(const f16x8*)&vtT[(16 * n + c) * AST + 32 + 8 * g];
            accO[n] = __builtin_amdgcn_mfma_f32_16x16x32_f16(pa0, b0, accO[n], 0, 0, 0);
            accO[n] = __builtin_amdgcn_mfma_f32_16x16x32_f16(pa1, b1, accO[n], 0, 0, 0);
        }
    }

    // ---- epilogue: fp32 x
#pragma unroll
    for (int r = 0; r < 4; ++r) {
        const float inv = (l_r[r] > 0.f) ? 1.0f / l_r[r] : 0.f;
        const int t = t0 + 16 * w + 4 * g + r;
#pragma unroll
        for (int n = 0; n < 4; ++n)
            xout[((size_t)(b * T_SEQ + t)) * FEAT + h * DKH + 16 * n + c] = accO[n][r] * inv;
    }
}

// ---------------------------------------------------------------------------
extern "C" void kernel_launch(void* const* d_in, const int* in_sizes, int n_in,
                              void* d_out, int out_size, void* d_ws, size_t ws_size,
                              hipStream_t stream)
{
    (void)in_sizes; (void)n_in; (void)out_size; (void)ws_size;
    const float* query   = (const float*)d_in[0];
    const float* key_in  = (const float*)d_in[1];
    const float* value   = (const float*)d_in[2];
    const float* pos_emb = (const float*)d_in[3];
    const int*   mask    = (const int*)  d_in[4];
    const float* Wq = (const float*)d_in[5];
    const float* bq = (const float*)d_in[6];
    const float* Wk = (const float*)d_in[7];
    const float* bk = (const float*)d_in[8];
    const float* Wv = (const float*)d_in[9];
    const float* bv = (const float*)d_in[10];
    const float* Wo = (const float*)d_in[11];
    const float* bo = (const float*)d_in[12];
    const float* Wp = (const float*)d_in[13];
    const float* pbu = (const float*)d_in[14];
    const float* pbv = (const float*)d_in[15];
    float* out = (float*)d_out;

    const size_t NTOK = (size_t)8 * T_SEQ;       // 8192
    char* wsp = (char*)d_ws;
    size_t off = 0;
    auto alloc = [&](size_t bytes) { char* p = wsp + off; off += (bytes + 255) & ~255ull; return p; };

    unsigned short* qbf = (unsigned short*)alloc(NTOK * FEAT * 2);        // f16
    unsigned short* kbf = (unsigned short*)alloc(NTOK * FEAT * 2);        // f16
    unsigned short* vTb = (unsigned short*)alloc(NTOK * FEAT * 2);        // f16 [b][feat][t]
    unsigned short* pbf = (unsigned short*)alloc((size_t)2047 * FEAT * 2);// f16
    float*          xbf = (float*)alloc(NTOK * FEAT * 4);                 // fp32
    unsigned short* wh[5]; unsigned short* wl[5];
    for (int i = 0; i < 5; ++i) {
        wh[i] = (unsigned short*)alloc((size_t)FEAT * FEAT * 2);
        wl[i] = (unsigned short*)alloc((size_t)FEAT * FEAT * 2);
    }

    WSplit sp;
    const float* wsrc[5] = {Wq, Wk, Wv, Wp, Wo};
    for (int i = 0; i < 5; ++i) { sp.src[i] = wsrc[i]; sp.hi[i] = wh[i]; sp.lo[i] = wl[i]; }
    split_weights<<<dim3(64, 5), 256, 0, stream>>>(sp);

    gemm_split<1><<<dim3(128, 8), 256, 0, stream>>>(query,  wh[0], wl[0], bq, qbf, 8192, FEAT, FEAT);
    gemm_split<1><<<dim3(128, 8), 256, 0, stream>>>(key_in, wh[1], wl[1], bk, kbf, 8192, FEAT, FEAT);
    gemm_split<2><<<dim3(128, 8), 256, 0, stream>>>(value,  wh[2], wl[2], bv, vTb, 8192, FEAT, FEAT);
    gemm_split<1><<<dim3(32, 8),  256, 0, stream>>>(pos_emb, wh[3], wl[3], nullptr, pbf, 2047, FEAT, FEAT);

    const int lds_bytes = (64 * AST * 3 + 128 * AST + 64 * BDST) * 2;   // 62976
    hipFuncSetAttribute((const void*)attn_f16,
                        hipFuncAttributeMaxDynamicSharedMemorySize, lds_bytes);
    attn_f16<<<dim3(16, 64), 256, lds_bytes, stream>>>(qbf, kbf, vTb, pbf,
                                                       mask, pbu, pbv, xbf);

    gemm_split<0><<<dim3(128, 8), 256, 0, stream>>>(xbf, wh[4], wl[4], bo, out, 8192, FEAT, FEAT);
}